// Round 1
// baseline (2998.326 us; speedup 1.0000x reference)
//
#include <hip/hip_runtime.h>
#include <hip/hip_bf16.h>

#define T_TOK 4096
#define DIM   2048
#define HID   1024
#define NE    16
#define CAPE  512

// ---------------- gate + coef kernel: one block per token ----------------
__global__ __launch_bounds__(256) void gate_kernel(
    const float* __restrict__ x, const float* __restrict__ gate_w,
    const float* __restrict__ coef_w, const float* __restrict__ coef_b,
    int* __restrict__ topidx, float* __restrict__ gatesw,
    float* __restrict__ coefo, float* __restrict__ probs_sum)
{
    __shared__ float xs[DIM];
    __shared__ float red[4][18];
    __shared__ float logits[18];
    int t = blockIdx.x;
    const float* xr = x + (size_t)t * DIM;
    for (int i = threadIdx.x; i < DIM; i += 256) xs[i] = xr[i];
    __syncthreads();
    float acc[18];
#pragma unroll
    for (int o = 0; o < 18; ++o) acc[o] = 0.f;
    for (int d = threadIdx.x; d < DIM; d += 256) {
        float xv = xs[d];
        const float* gw = gate_w + (size_t)d * NE;
#pragma unroll
        for (int o = 0; o < NE; ++o) acc[o] += xv * gw[o];
        acc[16] += xv * coef_w[d * 2 + 0];
        acc[17] += xv * coef_w[d * 2 + 1];
    }
#pragma unroll
    for (int off = 32; off > 0; off >>= 1) {
#pragma unroll
        for (int o = 0; o < 18; ++o) acc[o] += __shfl_down(acc[o], off, 64);
    }
    int wv = threadIdx.x >> 6, ln = threadIdx.x & 63;
    if (ln == 0) {
#pragma unroll
        for (int o = 0; o < 18; ++o) red[wv][o] = acc[o];
    }
    __syncthreads();
    if (threadIdx.x < 18) {
        logits[threadIdx.x] = red[0][threadIdx.x] + red[1][threadIdx.x]
                            + red[2][threadIdx.x] + red[3][threadIdx.x];
    }
    __syncthreads();
    if (threadIdx.x == 0) {
        float p[NE];
        float m = logits[0];
        for (int e = 1; e < NE; ++e) m = fmaxf(m, logits[e]);
        float ssum = 0.f;
        for (int e = 0; e < NE; ++e) { p[e] = expf(logits[e] - m); ssum += p[e]; }
        for (int e = 0; e < NE; ++e) p[e] /= ssum;
        // top-2, ties -> lower index (strict >)
        int i1 = 0;
        for (int e = 1; e < NE; ++e) if (p[e] > p[i1]) i1 = e;
        int i2 = -1;
        for (int e = 0; e < NE; ++e) { if (e == i1) continue; if (i2 < 0 || p[e] > p[i2]) i2 = e; }
        float g0 = p[i1], g1 = p[i2], gs = g0 + g1;
        topidx[t * 2 + 0] = i1; topidx[t * 2 + 1] = i2;
        gatesw[t * 2 + 0] = g0 / gs; gatesw[t * 2 + 1] = g1 / gs;
        float c0 = logits[16] + coef_b[0], c1 = logits[17] + coef_b[1];
        float cm = fmaxf(c0, c1);
        float e0 = expf(c0 - cm), e1 = expf(c1 - cm);
        float cs = e0 + e1;
        coefo[t * 2 + 0] = e0 / cs; coefo[t * 2 + 1] = e1 / cs;
        for (int e = 0; e < NE; ++e) atomicAdd(&probs_sum[e], p[e]);
    }
}

// ---------------- sequential capacity scan: single block ----------------
__global__ __launch_bounds__(256) void scan_kernel(
    const int* __restrict__ topidx, const float* __restrict__ gatesw,
    const float* __restrict__ probs_sum,
    int* __restrict__ sidx, float* __restrict__ swt,
    int* __restrict__ assign_token, int* __restrict__ nvalid,
    float* __restrict__ out_tail)
{
    __shared__ int run[NE];
    __shared__ int whist[4][NE];
    __shared__ int cnt0[NE];
    __shared__ int base[NE];
    int tid = threadIdx.x, wv = tid >> 6, ln = tid & 63;
    unsigned long long ltmask = (1ull << ln) - 1ull;

    for (int kk = 0; kk < 2; ++kk) {
        if (tid < NE) {
            if (kk == 0) base[tid] = 0;
            else { cnt0[tid] = run[tid]; base[tid] = run[tid]; }
            run[tid] = 0;
        }
        __syncthreads();
        for (int c = 0; c < T_TOK; c += 256) {
            int t = c + tid;
            int e = topidx[t * 2 + kk];
            int within = 0;
            for (int ee = 0; ee < NE; ++ee) {
                unsigned long long b = __ballot(e == ee);
                if (ee == e) within = __popcll(b & ltmask);
                if (ln == 0) whist[wv][ee] = __popcll(b);
            }
            __syncthreads();
            int cross = 0;
            for (int w = 0; w < wv; ++w) cross += whist[w][e];
            int loc = run[e] + cross + within;
            int pos = base[e] + loc;
            bool keep = pos < CAPE;
            sidx[t * 2 + kk] = keep ? (e * CAPE + pos) : -1;
            swt[t * 2 + kk] = keep ? gatesw[t * 2 + kk] : 0.f;
            if (keep) assign_token[e * CAPE + pos] = t;
            __syncthreads();
            if (tid < NE) {
                run[tid] += whist[0][tid] + whist[1][tid] + whist[2][tid] + whist[3][tid];
            }
            __syncthreads();
        }
    }
    if (tid < NE) {
        int c0v = cnt0[tid], c1v = run[tid];
        nvalid[tid] = min(CAPE, c0v + c1v);
        out_tail[1 + tid] = (float)(c0v + c1v);
    }
    __syncthreads();
    if (tid == 0) {
        float la = 0.f;
        for (int e = 0; e < NE; ++e)
            la += (probs_sum[e] / (float)T_TOK) * ((float)cnt0[e] / (float)T_TOK);
        out_tail[0] = la * (float)NE;
    }
}

// ---------------- shared MLP part1: h_s = silu(x@sw1) * (x@sw3) ----------------
__global__ __launch_bounds__(256) void mlp1_kernel(
    const float* __restrict__ x, const float* __restrict__ sw1,
    const float* __restrict__ sw3, float* __restrict__ h_s)
{
    __shared__ float As[64][16];
    __shared__ float B1s[16][64];
    __shared__ float B3s[16][64];
    int bm = blockIdx.x * 64, bn = blockIdx.y * 64;
    int tid = threadIdx.x;
    int tx = tid & 15, ty = tid >> 4;
    int ar = tid >> 2, ac = (tid & 3) << 2;
    int br = tid >> 4, bc = (tid & 15) << 2;
    float acc1[4][4] = {}, acc3[4][4] = {};
    for (int k0 = 0; k0 < DIM; k0 += 16) {
        float4 av = *(const float4*)(x + (size_t)(bm + ar) * DIM + k0 + ac);
        float4 b1 = *(const float4*)(sw1 + (size_t)(k0 + br) * HID + bn + bc);
        float4 b3 = *(const float4*)(sw3 + (size_t)(k0 + br) * HID + bn + bc);
        *(float4*)&As[ar][ac] = av;
        *(float4*)&B1s[br][bc] = b1;
        *(float4*)&B3s[br][bc] = b3;
        __syncthreads();
#pragma unroll
        for (int kk = 0; kk < 16; ++kk) {
            float a[4];
#pragma unroll
            for (int i = 0; i < 4; ++i) a[i] = As[ty * 4 + i][kk];
            float4 v1 = *(float4*)&B1s[kk][tx * 4];
            float4 v3 = *(float4*)&B3s[kk][tx * 4];
#pragma unroll
            for (int i = 0; i < 4; ++i) {
                acc1[i][0] += a[i] * v1.x; acc1[i][1] += a[i] * v1.y;
                acc1[i][2] += a[i] * v1.z; acc1[i][3] += a[i] * v1.w;
                acc3[i][0] += a[i] * v3.x; acc3[i][1] += a[i] * v3.y;
                acc3[i][2] += a[i] * v3.z; acc3[i][3] += a[i] * v3.w;
            }
        }
        __syncthreads();
    }
#pragma unroll
    for (int i = 0; i < 4; ++i) {
        int r = bm + ty * 4 + i;
        float4 o;
        float g;
        g = acc1[i][0]; o.x = g / (1.f + expf(-g)) * acc3[i][0];
        g = acc1[i][1]; o.y = g / (1.f + expf(-g)) * acc3[i][1];
        g = acc1[i][2]; o.z = g / (1.f + expf(-g)) * acc3[i][2];
        g = acc1[i][3]; o.w = g / (1.f + expf(-g)) * acc3[i][3];
        *(float4*)(h_s + (size_t)r * HID + bn + tx * 4) = o;
    }
}

// ---------------- shared MLP part2: out = coef1 * (h_s @ sw2) ----------------
__global__ __launch_bounds__(256) void mlp2_kernel(
    const float* __restrict__ h_s, const float* __restrict__ sw2,
    const float* __restrict__ coefo, float* __restrict__ out)
{
    __shared__ float As[64][16];
    __shared__ float Bs[16][64];
    int bm = blockIdx.x * 64, bn = blockIdx.y * 64;
    int tid = threadIdx.x;
    int tx = tid & 15, ty = tid >> 4;
    int ar = tid >> 2, ac = (tid & 3) << 2;
    int br = tid >> 4, bc = (tid & 15) << 2;
    float acc[4][4] = {};
    for (int k0 = 0; k0 < HID; k0 += 16) {
        float4 av = *(const float4*)(h_s + (size_t)(bm + ar) * HID + k0 + ac);
        float4 bv = *(const float4*)(sw2 + (size_t)(k0 + br) * DIM + bn + bc);
        *(float4*)&As[ar][ac] = av;
        *(float4*)&Bs[br][bc] = bv;
        __syncthreads();
#pragma unroll
        for (int kk = 0; kk < 16; ++kk) {
            float a[4];
#pragma unroll
            for (int i = 0; i < 4; ++i) a[i] = As[ty * 4 + i][kk];
            float4 bvv = *(float4*)&Bs[kk][tx * 4];
#pragma unroll
            for (int i = 0; i < 4; ++i) {
                acc[i][0] += a[i] * bvv.x; acc[i][1] += a[i] * bvv.y;
                acc[i][2] += a[i] * bvv.z; acc[i][3] += a[i] * bvv.w;
            }
        }
        __syncthreads();
    }
#pragma unroll
    for (int i = 0; i < 4; ++i) {
        int r = bm + ty * 4 + i;
        float c1 = coefo[r * 2 + 1];
        float4 o;
        o.x = c1 * acc[i][0]; o.y = c1 * acc[i][1];
        o.z = c1 * acc[i][2]; o.w = c1 * acc[i][3];
        *(float4*)(out + (size_t)r * DIM + bn + tx * 4) = o;
    }
}

// ---------------- expert part1: he = silu(Xe@w1) * (Xe@w3), gathered rows ----------------
__global__ __launch_bounds__(256) void exp1_kernel(
    const float* __restrict__ x, const float* __restrict__ w1,
    const float* __restrict__ w3, const int* __restrict__ assign_token,
    const int* __restrict__ nvalid, float* __restrict__ he)
{
    int e = blockIdx.z;
    int nv = nvalid[e];
    int bm = blockIdx.x * 64;
    if (bm >= nv) return;
    int bn = blockIdx.y * 64;
    __shared__ int toks[64];
    __shared__ float As[64][16];
    __shared__ float B1s[16][64];
    __shared__ float B3s[16][64];
    int tid = threadIdx.x;
    if (tid < 64) {
        int r = bm + tid;
        toks[tid] = (r < nv) ? assign_token[e * CAPE + r] : assign_token[e * CAPE];
    }
    __syncthreads();
    const float* W1 = w1 + (size_t)e * DIM * HID;
    const float* W3 = w3 + (size_t)e * DIM * HID;
    int tx = tid & 15, ty = tid >> 4;
    int ar = tid >> 2, ac = (tid & 3) << 2;
    int br = tid >> 4, bc = (tid & 15) << 2;
    float acc1[4][4] = {}, acc3[4][4] = {};
    for (int k0 = 0; k0 < DIM; k0 += 16) {
        float4 av = *(const float4*)(x + (size_t)toks[ar] * DIM + k0 + ac);
        float4 b1 = *(const float4*)(W1 + (size_t)(k0 + br) * HID + bn + bc);
        float4 b3 = *(const float4*)(W3 + (size_t)(k0 + br) * HID + bn + bc);
        *(float4*)&As[ar][ac] = av;
        *(float4*)&B1s[br][bc] = b1;
        *(float4*)&B3s[br][bc] = b3;
        __syncthreads();
#pragma unroll
        for (int kk = 0; kk < 16; ++kk) {
            float a[4];
#pragma unroll
            for (int i = 0; i < 4; ++i) a[i] = As[ty * 4 + i][kk];
            float4 v1 = *(float4*)&B1s[kk][tx * 4];
            float4 v3 = *(float4*)&B3s[kk][tx * 4];
#pragma unroll
            for (int i = 0; i < 4; ++i) {
                acc1[i][0] += a[i] * v1.x; acc1[i][1] += a[i] * v1.y;
                acc1[i][2] += a[i] * v1.z; acc1[i][3] += a[i] * v1.w;
                acc3[i][0] += a[i] * v3.x; acc3[i][1] += a[i] * v3.y;
                acc3[i][2] += a[i] * v3.z; acc3[i][3] += a[i] * v3.w;
            }
        }
        __syncthreads();
    }
#pragma unroll
    for (int i = 0; i < 4; ++i) {
        int r = bm + ty * 4 + i;
        float4 o;
        float g;
        g = acc1[i][0]; o.x = g / (1.f + expf(-g)) * acc3[i][0];
        g = acc1[i][1]; o.y = g / (1.f + expf(-g)) * acc3[i][1];
        g = acc1[i][2]; o.z = g / (1.f + expf(-g)) * acc3[i][2];
        g = acc1[i][3]; o.w = g / (1.f + expf(-g)) * acc3[i][3];
        *(float4*)(he + ((size_t)e * CAPE + r) * HID + bn + tx * 4) = o;
    }
}

// ---------------- expert part2: ye = he @ w2 ----------------
__global__ __launch_bounds__(256) void exp2_kernel(
    const float* __restrict__ he, const float* __restrict__ w2,
    const int* __restrict__ nvalid, float* __restrict__ ye)
{
    int e = blockIdx.z;
    int nv = nvalid[e];
    int bm = blockIdx.x * 64;
    if (bm >= nv) return;
    int bn = blockIdx.y * 64;
    __shared__ float As[64][16];
    __shared__ float Bs[16][64];
    int tid = threadIdx.x;
    const float* A = he + (size_t)e * CAPE * HID;
    const float* B = w2 + (size_t)e * HID * DIM;
    int tx = tid & 15, ty = tid >> 4;
    int ar = tid >> 2, ac = (tid & 3) << 2;
    int br = tid >> 4, bc = (tid & 15) << 2;
    float acc[4][4] = {};
    for (int k0 = 0; k0 < HID; k0 += 16) {
        float4 av = *(const float4*)(A + (size_t)(bm + ar) * HID + k0 + ac);
        float4 bv = *(const float4*)(B + (size_t)(k0 + br) * DIM + bn + bc);
        *(float4*)&As[ar][ac] = av;
        *(float4*)&Bs[br][bc] = bv;
        __syncthreads();
#pragma unroll
        for (int kk = 0; kk < 16; ++kk) {
            float a[4];
#pragma unroll
            for (int i = 0; i < 4; ++i) a[i] = As[ty * 4 + i][kk];
            float4 bvv = *(float4*)&Bs[kk][tx * 4];
#pragma unroll
            for (int i = 0; i < 4; ++i) {
                acc[i][0] += a[i] * bvv.x; acc[i][1] += a[i] * bvv.y;
                acc[i][2] += a[i] * bvv.z; acc[i][3] += a[i] * bvv.w;
            }
        }
        __syncthreads();
    }
#pragma unroll
    for (int i = 0; i < 4; ++i) {
        int r = bm + ty * 4 + i;
        float4 o;
        o.x = acc[i][0]; o.y = acc[i][1]; o.z = acc[i][2]; o.w = acc[i][3];
        *(float4*)(ye + ((size_t)e * CAPE + r) * DIM + bn + tx * 4) = o;
    }
}

// ---------------- final combine: out += coef0*(w0*ye[s0] + w1*ye[s1]) ----------------
__global__ __launch_bounds__(256) void combine_kernel(
    const float* __restrict__ ye, const int* __restrict__ sidx,
    const float* __restrict__ swt, const float* __restrict__ coefo,
    float* __restrict__ out)
{
    int idx = blockIdx.x * 256 + threadIdx.x; // one float4 per thread
    int t = idx >> 9;                          // 512 float4 per row
    int d = (idx & 511) << 2;
    int s0 = sidx[t * 2], s1 = sidx[t * 2 + 1];
    float c0 = coefo[t * 2];
    float w0 = swt[t * 2] * c0, w1 = swt[t * 2 + 1] * c0;
    float4 v = *(float4*)(out + (size_t)t * DIM + d);
    if (s0 >= 0) {
        float4 y = *(const float4*)(ye + (size_t)s0 * DIM + d);
        v.x += w0 * y.x; v.y += w0 * y.y; v.z += w0 * y.z; v.w += w0 * y.w;
    }
    if (s1 >= 0) {
        float4 y = *(const float4*)(ye + (size_t)s1 * DIM + d);
        v.x += w1 * y.x; v.y += w1 * y.y; v.z += w1 * y.z; v.w += w1 * y.w;
    }
    *(float4*)(out + (size_t)t * DIM + d) = v;
}

extern "C" void kernel_launch(void* const* d_in, const int* in_sizes, int n_in,
                              void* d_out, int out_size, void* d_ws, size_t ws_size,
                              hipStream_t stream)
{
    const float* x      = (const float*)d_in[0];
    const float* gate_w = (const float*)d_in[1];
    const float* w1     = (const float*)d_in[2];
    const float* w3     = (const float*)d_in[3];
    const float* w2     = (const float*)d_in[4];
    const float* sw1    = (const float*)d_in[5];
    const float* sw3    = (const float*)d_in[6];
    const float* sw2    = (const float*)d_in[7];
    const float* coef_w = (const float*)d_in[8];
    const float* coef_b = (const float*)d_in[9];
    float* out = (float*)d_out;

    char* ws = (char*)d_ws;
    size_t off = 0;
    auto alloc = [&](size_t bytes) -> void* {
        void* p = ws + off;
        off += (bytes + 255) & ~(size_t)255;
        return p;
    };
    float* probs_sum    = (float*)alloc(NE * 4);
    int*   nvalid       = (int*)alloc(NE * 4);
    int*   topidx       = (int*)alloc((size_t)T_TOK * 2 * 4);
    float* gatesw       = (float*)alloc((size_t)T_TOK * 2 * 4);
    float* coefo        = (float*)alloc((size_t)T_TOK * 2 * 4);
    int*   sidx         = (int*)alloc((size_t)T_TOK * 2 * 4);
    float* swt          = (float*)alloc((size_t)T_TOK * 2 * 4);
    int*   assign_token = (int*)alloc((size_t)NE * CAPE * 4);
    float* h_s          = (float*)alloc((size_t)T_TOK * HID * 4);
    float* he           = (float*)alloc((size_t)NE * CAPE * HID * 4);
    float* ye           = (float*)alloc((size_t)NE * CAPE * DIM * 4);

    hipMemsetAsync(probs_sum, 0, NE * 4, stream);
    gate_kernel<<<T_TOK, 256, 0, stream>>>(x, gate_w, coef_w, coef_b,
                                           topidx, gatesw, coefo, probs_sum);
    scan_kernel<<<1, 256, 0, stream>>>(topidx, gatesw, probs_sum,
                                       sidx, swt, assign_token, nvalid,
                                       out + (size_t)T_TOK * DIM);
    mlp1_kernel<<<dim3(T_TOK / 64, HID / 64), 256, 0, stream>>>(x, sw1, sw3, h_s);
    exp1_kernel<<<dim3(CAPE / 64, HID / 64, NE), 256, 0, stream>>>(x, w1, w3, assign_token, nvalid, he);
    mlp2_kernel<<<dim3(T_TOK / 64, DIM / 64), 256, 0, stream>>>(h_s, sw2, coefo, out);
    exp2_kernel<<<dim3(CAPE / 64, DIM / 64, NE), 256, 0, stream>>>(he, w2, nvalid, ye);
    combine_kernel<<<(T_TOK * (DIM / 4)) / 256, 256, 0, stream>>>(ye, sidx, swt, coefo, out);
}

// Round 2
// 1392.448 us; speedup vs baseline: 2.1533x; 2.1533x over previous
//
#include <hip/hip_runtime.h>
#include <hip/hip_bf16.h>
#include <stdint.h>

#define T_TOK 4096
#define DIM   2048
#define HID   1024
#define NE    16
#define CAPE  512

typedef __bf16 bf16x8 __attribute__((ext_vector_type(8)));
typedef float  f32x4  __attribute__((ext_vector_type(4)));

__device__ __forceinline__ ushort f2bf(float f) {
    union { float f; uint32_t u; } v; v.f = f;
    uint32_t r = (v.u + 0x7FFFu + ((v.u >> 16) & 1u)) >> 16;
    return (ushort)r;
}
__device__ __forceinline__ float bf2f(ushort u) {
    union { uint32_t u; float f; } v; v.u = (uint32_t)u << 16; return v.f;
}
__device__ __forceinline__ void gload16(const void* g, void* lds) {
    __builtin_amdgcn_global_load_lds(
        (const __attribute__((address_space(1))) uint32_t*)g,
        (__attribute__((address_space(3))) uint32_t*)lds, 16, 0, 0);
}

// ---------------- gate + coef kernel: one block per token ----------------
__global__ __launch_bounds__(256) void gate_kernel(
    const float* __restrict__ x, const float* __restrict__ gate_w,
    const float* __restrict__ coef_w, const float* __restrict__ coef_b,
    int* __restrict__ topidx, float* __restrict__ gatesw,
    float* __restrict__ coefo, float* __restrict__ probs_sum)
{
    __shared__ float xs[DIM];
    __shared__ float red[4][18];
    __shared__ float logits[18];
    int t = blockIdx.x;
    const float* xr = x + (size_t)t * DIM;
    for (int i = threadIdx.x; i < DIM; i += 256) xs[i] = xr[i];
    __syncthreads();
    float acc[18];
#pragma unroll
    for (int o = 0; o < 18; ++o) acc[o] = 0.f;
    for (int d = threadIdx.x; d < DIM; d += 256) {
        float xv = xs[d];
        const float* gw = gate_w + (size_t)d * NE;
#pragma unroll
        for (int o = 0; o < NE; ++o) acc[o] += xv * gw[o];
        acc[16] += xv * coef_w[d * 2 + 0];
        acc[17] += xv * coef_w[d * 2 + 1];
    }
#pragma unroll
    for (int off = 32; off > 0; off >>= 1) {
#pragma unroll
        for (int o = 0; o < 18; ++o) acc[o] += __shfl_down(acc[o], off, 64);
    }
    int wv = threadIdx.x >> 6, ln = threadIdx.x & 63;
    if (ln == 0) {
#pragma unroll
        for (int o = 0; o < 18; ++o) red[wv][o] = acc[o];
    }
    __syncthreads();
    if (threadIdx.x < 18) {
        logits[threadIdx.x] = red[0][threadIdx.x] + red[1][threadIdx.x]
                            + red[2][threadIdx.x] + red[3][threadIdx.x];
    }
    __syncthreads();
    if (threadIdx.x == 0) {
        float p[NE];
        float m = logits[0];
        for (int e = 1; e < NE; ++e) m = fmaxf(m, logits[e]);
        float ssum = 0.f;
        for (int e = 0; e < NE; ++e) { p[e] = expf(logits[e] - m); ssum += p[e]; }
        for (int e = 0; e < NE; ++e) p[e] /= ssum;
        int i1 = 0;
        for (int e = 1; e < NE; ++e) if (p[e] > p[i1]) i1 = e;
        int i2 = -1;
        for (int e = 0; e < NE; ++e) { if (e == i1) continue; if (i2 < 0 || p[e] > p[i2]) i2 = e; }
        float g0 = p[i1], g1 = p[i2], gs = g0 + g1;
        topidx[t * 2 + 0] = i1; topidx[t * 2 + 1] = i2;
        gatesw[t * 2 + 0] = g0 / gs; gatesw[t * 2 + 1] = g1 / gs;
        float c0 = logits[16] + coef_b[0], c1 = logits[17] + coef_b[1];
        float cm = fmaxf(c0, c1);
        float e0 = expf(c0 - cm), e1 = expf(c1 - cm);
        float cs = e0 + e1;
        coefo[t * 2 + 0] = e0 / cs; coefo[t * 2 + 1] = e1 / cs;
        for (int e = 0; e < NE; ++e) atomicAdd(&probs_sum[e], p[e]);
    }
}

// ---------------- sequential capacity scan: single block ----------------
__global__ __launch_bounds__(256) void scan_kernel(
    const int* __restrict__ topidx, const float* __restrict__ gatesw,
    const float* __restrict__ probs_sum,
    int* __restrict__ sidx, float* __restrict__ swt,
    int* __restrict__ assign_token, int* __restrict__ nvalid,
    float* __restrict__ out_tail)
{
    __shared__ int run[NE];
    __shared__ int whist[4][NE];
    __shared__ int cnt0[NE];
    __shared__ int base[NE];
    int tid = threadIdx.x, wv = tid >> 6, ln = tid & 63;
    unsigned long long ltmask = (1ull << ln) - 1ull;

    for (int kk = 0; kk < 2; ++kk) {
        if (tid < NE) {
            if (kk == 0) base[tid] = 0;
            else { cnt0[tid] = run[tid]; base[tid] = run[tid]; }
            run[tid] = 0;
        }
        __syncthreads();
        for (int c = 0; c < T_TOK; c += 256) {
            int t = c + tid;
            int e = topidx[t * 2 + kk];
            int within = 0;
            for (int ee = 0; ee < NE; ++ee) {
                unsigned long long b = __ballot(e == ee);
                if (ee == e) within = __popcll(b & ltmask);
                if (ln == 0) whist[wv][ee] = __popcll(b);
            }
            __syncthreads();
            int cross = 0;
            for (int w = 0; w < wv; ++w) cross += whist[w][e];
            int loc = run[e] + cross + within;
            int pos = base[e] + loc;
            bool keep = pos < CAPE;
            sidx[t * 2 + kk] = keep ? (e * CAPE + pos) : -1;
            swt[t * 2 + kk] = keep ? gatesw[t * 2 + kk] : 0.f;
            if (keep) assign_token[e * CAPE + pos] = t;
            __syncthreads();
            if (tid < NE) {
                run[tid] += whist[0][tid] + whist[1][tid] + whist[2][tid] + whist[3][tid];
            }
            __syncthreads();
        }
    }
    if (tid < NE) {
        int c0v = cnt0[tid], c1v = run[tid];
        nvalid[tid] = min(CAPE, c0v + c1v);
        out_tail[1 + tid] = (float)(c0v + c1v);
    }
    __syncthreads();
    if (tid == 0) {
        float la = 0.f;
        for (int e = 0; e < NE; ++e)
            la += (probs_sum[e] / (float)T_TOK) * ((float)cnt0[e] / (float)T_TOK);
        out_tail[0] = la * (float)NE;
    }
}

// ---------------- transpose + convert: f32 [R][C] -> bf16 [C][R] ----------------
__global__ __launch_bounds__(256) void transpose_kernel(
    const float* __restrict__ in, ushort* __restrict__ out,
    int R, int C, size_t IEs, size_t OEs)
{
    __shared__ __align__(16) ushort tile[64][72];
    int e = blockIdx.z;
    const float* ie = in + (size_t)e * IEs;
    ushort* oe = out + (size_t)e * OEs;
    int r0 = blockIdx.x * 64, c0 = blockIdx.y * 64;
    int tid = threadIdx.x;
    int rr = tid >> 4, cc = (tid & 15) * 4;
#pragma unroll
    for (int i = 0; i < 4; ++i) {
        int r = i * 16 + rr;
        float4 v = *(const float4*)(ie + (size_t)(r0 + r) * C + c0 + cc);
        tile[cc + 0][r] = f2bf(v.x);
        tile[cc + 1][r] = f2bf(v.y);
        tile[cc + 2][r] = f2bf(v.z);
        tile[cc + 3][r] = f2bf(v.w);
    }
    __syncthreads();
    int oc = tid >> 3, orr = (tid & 7) * 8;
#pragma unroll
    for (int i = 0; i < 2; ++i) {
        int c = i * 32 + oc;
        uint4 v = *(const uint4*)&tile[c][orr];
        *(uint4*)(oe + (size_t)(c0 + c) * R + r0 + orr) = v;
    }
}

// ---------------- f32 -> bf16 convert (contiguous) ----------------
__global__ __launch_bounds__(256) void convert_kernel(
    const float* __restrict__ in, ushort* __restrict__ out)
{
    int i = (blockIdx.x * 256 + threadIdx.x) * 8;
    float4 a = *(const float4*)(in + i);
    float4 b = *(const float4*)(in + i + 4);
    ushort o[8];
    o[0] = f2bf(a.x); o[1] = f2bf(a.y); o[2] = f2bf(a.z); o[3] = f2bf(a.w);
    o[4] = f2bf(b.x); o[5] = f2bf(b.y); o[6] = f2bf(b.z); o[7] = f2bf(b.w);
    *(uint4*)(out + i) = *(uint4*)o;
}

// ---------------- gather tokens -> dense bf16 [E*CAPE][DIM], zero-fill ----------------
__global__ __launch_bounds__(256) void gather_kernel(
    const float* __restrict__ x, const int* __restrict__ assign_token,
    const int* __restrict__ nvalid, ushort* __restrict__ xg)
{
    int slot = blockIdx.x;
    int e = slot >> 9, c = slot & (CAPE - 1);
    int tid = threadIdx.x;
    ushort o[8];
    if (c < nvalid[e]) {
        int tok = assign_token[slot];
        const float* src = x + (size_t)tok * DIM + tid * 8;
        float4 a = *(const float4*)src;
        float4 b = *(const float4*)(src + 4);
        o[0] = f2bf(a.x); o[1] = f2bf(a.y); o[2] = f2bf(a.z); o[3] = f2bf(a.w);
        o[4] = f2bf(b.x); o[5] = f2bf(b.y); o[6] = f2bf(b.z); o[7] = f2bf(b.w);
    } else {
#pragma unroll
        for (int j = 0; j < 8; ++j) o[j] = 0;
    }
    *(uint4*)(xg + (size_t)slot * DIM + tid * 8) = *(uint4*)o;
}

// ---------------- bf16 MFMA GEMM, m97 structure: C = A @ B^T ----------------
// A: [M][K] bf16 (row stride K), B: [N][K] bf16 (row stride K)
// MODE 0: bf16 out; 1: bf16 out = silu(aux)*acc (in-place ok); 2: f32 out; 3: f32 out * rowscale[2*row]
template<int MODE>
__global__ __launch_bounds__(256) void gemm_bt(
    const ushort* __restrict__ A, const ushort* __restrict__ B,
    void* __restrict__ Out, const ushort* __restrict__ aux,
    const float* __restrict__ rowscale,
    int K, int outstride,
    size_t Aes, size_t Bes, size_t Oes, size_t Xes,
    const int* __restrict__ nvalid)
{
    int e = blockIdx.z;
    int bm = blockIdx.x * 128, bn = blockIdx.y * 128;
    if (nvalid && bm >= nvalid[e]) return;
    const ushort* Ae = A + (size_t)e * Aes;
    const ushort* Be = B + (size_t)e * Bes;

    __shared__ __align__(16) ushort As[128 * 64];
    __shared__ __align__(16) ushort Bs[128 * 64];

    int tid = threadIdx.x;
    int lane = tid & 63;
    int wr = (tid >> 7) & 1;
    int wc = (tid >> 6) & 1;

    f32x4 acc[4][4];
#pragma unroll
    for (int m = 0; m < 4; ++m)
#pragma unroll
        for (int n = 0; n < 4; ++n)
            acc[m][n] = (f32x4){0.f, 0.f, 0.f, 0.f};

    for (int k0 = 0; k0 < K; k0 += 64) {
#pragma unroll
        for (int j = 0; j < 4; ++j) {
            int c = j * 256 + tid;
            int r = c >> 3, ce = (c & 7) * 8;
            gload16(Ae + (size_t)(bm + r) * K + k0 + ce, &As[(c - lane) * 8]);
        }
#pragma unroll
        for (int j = 0; j < 4; ++j) {
            int c = j * 256 + tid;
            int r = c >> 3, ce = (c & 7) * 8;
            gload16(Be + (size_t)(bn + r) * K + k0 + ce, &Bs[(c - lane) * 8]);
        }
        __syncthreads();
#pragma unroll
        for (int ks = 0; ks < 2; ++ks) {
            int kb = ks * 32 + (lane >> 4) * 8;
            bf16x8 a[4], b[4];
#pragma unroll
            for (int m = 0; m < 4; ++m)
                a[m] = *(const bf16x8*)&As[(wr * 64 + m * 16 + (lane & 15)) * 64 + kb];
#pragma unroll
            for (int n = 0; n < 4; ++n)
                b[n] = *(const bf16x8*)&Bs[(wc * 64 + n * 16 + (lane & 15)) * 64 + kb];
#pragma unroll
            for (int m = 0; m < 4; ++m)
#pragma unroll
                for (int n = 0; n < 4; ++n)
                    acc[m][n] = __builtin_amdgcn_mfma_f32_16x16x32_bf16(a[m], b[n], acc[m][n], 0, 0, 0);
        }
        __syncthreads();
    }

    ushort* Ob = (ushort*)Out + (size_t)e * Oes;
    float*  Of = (float*)Out + (size_t)e * Oes;
    const ushort* Xe = aux + (size_t)e * Xes;
    int rbase = bm + wr * 64 + (lane >> 4) * 4;
    int cbase = bn + wc * 64 + (lane & 15);
#pragma unroll
    for (int m = 0; m < 4; ++m) {
#pragma unroll
        for (int n = 0; n < 4; ++n) {
            int col = cbase + n * 16;
#pragma unroll
            for (int r = 0; r < 4; ++r) {
                int row = rbase + m * 16 + r;
                float v = acc[m][n][r];
                if (MODE == 0) {
                    Ob[(size_t)row * outstride + col] = f2bf(v);
                } else if (MODE == 1) {
                    float g = bf2f(Xe[(size_t)row * outstride + col]);
                    float s = g / (1.f + __expf(-g));
                    Ob[(size_t)row * outstride + col] = f2bf(s * v);
                } else if (MODE == 2) {
                    Of[(size_t)row * outstride + col] = v;
                } else {
                    Of[(size_t)row * outstride + col] = v * rowscale[2 * row];
                }
            }
        }
    }
}

// ---------------- final combine: out += coef0*(w0*ye[s0] + w1*ye[s1]) ----------------
__global__ __launch_bounds__(256) void combine_kernel(
    const float* __restrict__ ye, const int* __restrict__ sidx,
    const float* __restrict__ swt, const float* __restrict__ coefo,
    float* __restrict__ out)
{
    int idx = blockIdx.x * 256 + threadIdx.x;
    int t = idx >> 9;
    int d = (idx & 511) << 2;
    int s0 = sidx[t * 2], s1 = sidx[t * 2 + 1];
    float c0 = coefo[t * 2];
    float w0 = swt[t * 2] * c0, w1 = swt[t * 2 + 1] * c0;
    float4 v = *(float4*)(out + (size_t)t * DIM + d);
    if (s0 >= 0) {
        float4 y = *(const float4*)(ye + (size_t)s0 * DIM + d);
        v.x += w0 * y.x; v.y += w0 * y.y; v.z += w0 * y.z; v.w += w0 * y.w;
    }
    if (s1 >= 0) {
        float4 y = *(const float4*)(ye + (size_t)s1 * DIM + d);
        v.x += w1 * y.x; v.y += w1 * y.y; v.z += w1 * y.z; v.w += w1 * y.w;
    }
    *(float4*)(out + (size_t)t * DIM + d) = v;
}

extern "C" void kernel_launch(void* const* d_in, const int* in_sizes, int n_in,
                              void* d_out, int out_size, void* d_ws, size_t ws_size,
                              hipStream_t stream)
{
    const float* x      = (const float*)d_in[0];
    const float* gate_w = (const float*)d_in[1];
    const float* w1     = (const float*)d_in[2];
    const float* w3     = (const float*)d_in[3];
    const float* w2     = (const float*)d_in[4];
    const float* sw1    = (const float*)d_in[5];
    const float* sw3    = (const float*)d_in[6];
    const float* sw2    = (const float*)d_in[7];
    const float* coef_w = (const float*)d_in[8];
    const float* coef_b = (const float*)d_in[9];
    float* out = (float*)d_out;

    char* ws = (char*)d_ws;
    size_t off = 0;
    auto alloc = [&](size_t bytes) -> void* {
        void* p = ws + off;
        off += (bytes + 255) & ~(size_t)255;
        return p;
    };
    float*  probs_sum    = (float*)alloc(NE * 4);
    int*    nvalid       = (int*)alloc(NE * 4);
    int*    topidx       = (int*)alloc((size_t)T_TOK * 2 * 4);
    float*  gatesw       = (float*)alloc((size_t)T_TOK * 2 * 4);
    float*  coefo        = (float*)alloc((size_t)T_TOK * 2 * 4);
    int*    sidx         = (int*)alloc((size_t)T_TOK * 2 * 4);
    float*  swt          = (float*)alloc((size_t)T_TOK * 2 * 4);
    int*    assign_token = (int*)alloc((size_t)NE * CAPE * 4);
    ushort* w1T  = (ushort*)alloc((size_t)NE * HID * DIM * 2);
    ushort* w3T  = (ushort*)alloc((size_t)NE * HID * DIM * 2);
    ushort* w2T  = (ushort*)alloc((size_t)NE * DIM * HID * 2);
    ushort* sw1T = (ushort*)alloc((size_t)HID * DIM * 2);
    ushort* sw3T = (ushort*)alloc((size_t)HID * DIM * 2);
    ushort* sw2T = (ushort*)alloc((size_t)DIM * HID * 2);
    ushort* xb   = (ushort*)alloc((size_t)T_TOK * DIM * 2);
    ushort* xg   = (ushort*)alloc((size_t)NE * CAPE * DIM * 2);
    ushort* h1   = (ushort*)alloc((size_t)T_TOK * HID * 2);
    ushort* he1  = (ushort*)alloc((size_t)NE * CAPE * HID * 2);
    float*  ye   = (float*)alloc((size_t)NE * CAPE * DIM * 4);

    hipMemsetAsync(probs_sum, 0, NE * 4, stream);
    gate_kernel<<<T_TOK, 256, 0, stream>>>(x, gate_w, coef_w, coef_b,
                                           topidx, gatesw, coefo, probs_sum);
    scan_kernel<<<1, 256, 0, stream>>>(topidx, gatesw, probs_sum,
                                       sidx, swt, assign_token, nvalid,
                                       out + (size_t)T_TOK * DIM);

    // weight transposes + x convert
    transpose_kernel<<<dim3(DIM/64, HID/64, NE), 256, 0, stream>>>(w1, w1T, DIM, HID, (size_t)DIM*HID, (size_t)HID*DIM);
    transpose_kernel<<<dim3(DIM/64, HID/64, NE), 256, 0, stream>>>(w3, w3T, DIM, HID, (size_t)DIM*HID, (size_t)HID*DIM);
    transpose_kernel<<<dim3(HID/64, DIM/64, NE), 256, 0, stream>>>(w2, w2T, HID, DIM, (size_t)HID*DIM, (size_t)DIM*HID);
    transpose_kernel<<<dim3(DIM/64, HID/64, 1), 256, 0, stream>>>(sw1, sw1T, DIM, HID, 0, 0);
    transpose_kernel<<<dim3(DIM/64, HID/64, 1), 256, 0, stream>>>(sw3, sw3T, DIM, HID, 0, 0);
    transpose_kernel<<<dim3(HID/64, DIM/64, 1), 256, 0, stream>>>(sw2, sw2T, HID, DIM, 0, 0);
    convert_kernel<<<(T_TOK * DIM) / (256 * 8), 256, 0, stream>>>(x, xb);
    gather_kernel<<<NE * CAPE, 256, 0, stream>>>(x, assign_token, nvalid, xg);

    // shared MLP: h1 = xb@sw1T; h1 = silu(h1)*(xb@sw3T); out = (h1@sw2T)*c1
    gemm_bt<0><<<dim3(T_TOK/128, HID/128, 1), 256, 0, stream>>>(
        xb, sw1T, h1, h1, nullptr, DIM, HID, 0, 0, 0, 0, nullptr);
    gemm_bt<1><<<dim3(T_TOK/128, HID/128, 1), 256, 0, stream>>>(
        xb, sw3T, h1, h1, nullptr, DIM, HID, 0, 0, 0, 0, nullptr);

    // experts: he1 = xg@w1T; he1 = silu(he1)*(xg@w3T); ye = he1@w2T
    gemm_bt<0><<<dim3(CAPE/128, HID/128, NE), 256, 0, stream>>>(
        xg, w1T, he1, he1, nullptr, DIM, HID,
        (size_t)CAPE*DIM, (size_t)HID*DIM, (size_t)CAPE*HID, (size_t)CAPE*HID, nvalid);
    gemm_bt<1><<<dim3(CAPE/128, HID/128, NE), 256, 0, stream>>>(
        xg, w3T, he1, he1, nullptr, DIM, HID,
        (size_t)CAPE*DIM, (size_t)HID*DIM, (size_t)CAPE*HID, (size_t)CAPE*HID, nvalid);
    gemm_bt<2><<<dim3(CAPE/128, DIM/128, NE), 256, 0, stream>>>(
        he1, w2T, ye, he1, nullptr, HID, DIM,
        (size_t)CAPE*HID, (size_t)DIM*HID, (size_t)CAPE*DIM, 0, nvalid);

    gemm_bt<3><<<dim3(T_TOK/128, DIM/128, 1), 256, 0, stream>>>(
        h1, sw2T, out, h1, coefo + 1, HID, DIM, 0, 0, 0, 0, nullptr);

    combine_kernel<<<(T_TOK * (DIM / 4)) / 256, 256, 0, stream>>>(ye, sidx, swt, coefo, out);
}

// Round 3
// 582.911 us; speedup vs baseline: 5.1437x; 2.3888x over previous
//
#include <hip/hip_runtime.h>
#include <hip/hip_bf16.h>
#include <stdint.h>

#define T_TOK 4096
#define DIM   2048
#define HID   1024
#define NE    16
#define CAPE  512

typedef __bf16 bf16x8 __attribute__((ext_vector_type(8)));
typedef float  f32x4  __attribute__((ext_vector_type(4)));

__device__ __forceinline__ ushort f2bf(float f) {
    union { float f; uint32_t u; } v; v.f = f;
    uint32_t r = (v.u + 0x7FFFu + ((v.u >> 16) & 1u)) >> 16;
    return (ushort)r;
}
__device__ __forceinline__ float bf2f(ushort u) {
    union { uint32_t u; float f; } v; v.u = (uint32_t)u << 16; return v.f;
}
__device__ __forceinline__ void gload16(const void* g, void* lds) {
    __builtin_amdgcn_global_load_lds(
        (const __attribute__((address_space(1))) uint32_t*)g,
        (__attribute__((address_space(3))) uint32_t*)lds, 16, 0, 0);
}

// ---------------- logits: one wave per token, 18 outputs ----------------
__global__ __launch_bounds__(256) void logits_kernel(
    const float* __restrict__ x, const float* __restrict__ gate_w,
    const float* __restrict__ coef_w, float* __restrict__ logits)
{
    int t = blockIdx.x * 4 + (threadIdx.x >> 6);
    int lane = threadIdx.x & 63;
    const float* xr = x + (size_t)t * DIM;
    float acc[18];
#pragma unroll
    for (int o = 0; o < 18; ++o) acc[o] = 0.f;
    for (int d = lane; d < DIM; d += 64) {
        float xv = xr[d];
        const float* gw = gate_w + (size_t)d * NE;
#pragma unroll
        for (int o = 0; o < NE; ++o) acc[o] += xv * gw[o];
        acc[16] += xv * coef_w[d * 2 + 0];
        acc[17] += xv * coef_w[d * 2 + 1];
    }
#pragma unroll
    for (int off = 32; off > 0; off >>= 1) {
#pragma unroll
        for (int o = 0; o < 18; ++o) acc[o] += __shfl_down(acc[o], off, 64);
    }
    if (lane == 0) {
#pragma unroll
        for (int o = 0; o < 18; ++o) logits[(size_t)t * 18 + o] = acc[o];
    }
}

// ---------------- finish: one thread per token ----------------
__global__ __launch_bounds__(256) void finish_kernel(
    const float* __restrict__ logits, const float* __restrict__ coef_b,
    int* __restrict__ topidx, float* __restrict__ gatesw,
    float* __restrict__ coefo, float* __restrict__ probs_sum)
{
    __shared__ float wred[4][NE];
    int t = blockIdx.x * 256 + threadIdx.x;
    float lg[18];
#pragma unroll
    for (int o = 0; o < 18; ++o) lg[o] = logits[(size_t)t * 18 + o];
    float p[NE];
    float m = lg[0];
#pragma unroll
    for (int e = 1; e < NE; ++e) m = fmaxf(m, lg[e]);
    float ssum = 0.f;
#pragma unroll
    for (int e = 0; e < NE; ++e) { p[e] = expf(lg[e] - m); ssum += p[e]; }
    float inv = 1.f / ssum;
#pragma unroll
    for (int e = 0; e < NE; ++e) p[e] *= inv;
    int i1 = 0;
#pragma unroll
    for (int e = 1; e < NE; ++e) if (p[e] > p[i1]) i1 = e;
    int i2 = -1;
#pragma unroll
    for (int e = 0; e < NE; ++e) { if (e == i1) continue; if (i2 < 0 || p[e] > p[i2]) i2 = e; }
    float g0 = p[i1], g1 = p[i2], gs = g0 + g1;
    topidx[t * 2 + 0] = i1; topidx[t * 2 + 1] = i2;
    gatesw[t * 2 + 0] = g0 / gs; gatesw[t * 2 + 1] = g1 / gs;
    float c0 = lg[16] + coef_b[0], c1 = lg[17] + coef_b[1];
    float cm = fmaxf(c0, c1);
    float e0 = expf(c0 - cm), e1 = expf(c1 - cm);
    float cs = e0 + e1;
    coefo[t * 2 + 0] = e0 / cs; coefo[t * 2 + 1] = e1 / cs;

    // partial reduction of p over tokens: wave shuffle -> LDS -> 16 atomics/block
    float r[NE];
#pragma unroll
    for (int e = 0; e < NE; ++e) r[e] = p[e];
#pragma unroll
    for (int off = 32; off > 0; off >>= 1) {
#pragma unroll
        for (int e = 0; e < NE; ++e) r[e] += __shfl_down(r[e], off, 64);
    }
    int wv = threadIdx.x >> 6, ln = threadIdx.x & 63;
    if (ln == 0) {
#pragma unroll
        for (int e = 0; e < NE; ++e) wred[wv][e] = r[e];
    }
    __syncthreads();
    if (threadIdx.x < NE) {
        float s = wred[0][threadIdx.x] + wred[1][threadIdx.x]
                + wred[2][threadIdx.x] + wred[3][threadIdx.x];
        atomicAdd(&probs_sum[threadIdx.x], s);
    }
}

// ---------------- sequential capacity scan: single block ----------------
__global__ __launch_bounds__(256) void scan_kernel(
    const int* __restrict__ topidx, const float* __restrict__ gatesw,
    const float* __restrict__ probs_sum,
    int* __restrict__ sidx, float* __restrict__ swt,
    int* __restrict__ assign_token, int* __restrict__ nvalid,
    float* __restrict__ out_tail)
{
    __shared__ int run[NE];
    __shared__ int whist[4][NE];
    __shared__ int cnt0[NE];
    __shared__ int base[NE];
    int tid = threadIdx.x, wv = tid >> 6, ln = tid & 63;
    unsigned long long ltmask = (1ull << ln) - 1ull;

    for (int kk = 0; kk < 2; ++kk) {
        if (tid < NE) {
            if (kk == 0) base[tid] = 0;
            else { cnt0[tid] = run[tid]; base[tid] = run[tid]; }
            run[tid] = 0;
        }
        __syncthreads();
        for (int c = 0; c < T_TOK; c += 256) {
            int t = c + tid;
            int e = topidx[t * 2 + kk];
            int within = 0;
            for (int ee = 0; ee < NE; ++ee) {
                unsigned long long b = __ballot(e == ee);
                if (ee == e) within = __popcll(b & ltmask);
                if (ln == 0) whist[wv][ee] = __popcll(b);
            }
            __syncthreads();
            int cross = 0;
            for (int w = 0; w < wv; ++w) cross += whist[w][e];
            int loc = run[e] + cross + within;
            int pos = base[e] + loc;
            bool keep = pos < CAPE;
            sidx[t * 2 + kk] = keep ? (e * CAPE + pos) : -1;
            swt[t * 2 + kk] = keep ? gatesw[t * 2 + kk] : 0.f;
            if (keep) assign_token[e * CAPE + pos] = t;
            __syncthreads();
            if (tid < NE) {
                run[tid] += whist[0][tid] + whist[1][tid] + whist[2][tid] + whist[3][tid];
            }
            __syncthreads();
        }
    }
    if (tid < NE) {
        int c0v = cnt0[tid], c1v = run[tid];
        nvalid[tid] = min(CAPE, c0v + c1v);
        out_tail[1 + tid] = (float)(c0v + c1v);
    }
    __syncthreads();
    if (tid == 0) {
        float la = 0.f;
        for (int e = 0; e < NE; ++e)
            la += (probs_sum[e] / (float)T_TOK) * ((float)cnt0[e] / (float)T_TOK);
        out_tail[0] = la * (float)NE;
    }
}

// ---------------- transpose + convert: f32 [R][C] -> bf16 [C][R] ----------------
__global__ __launch_bounds__(256) void transpose_kernel(
    const float* __restrict__ in, ushort* __restrict__ out,
    int R, int C, size_t IEs, size_t OEs)
{
    __shared__ __align__(16) ushort tile[64][72];
    int e = blockIdx.z;
    const float* ie = in + (size_t)e * IEs;
    ushort* oe = out + (size_t)e * OEs;
    int r0 = blockIdx.x * 64, c0 = blockIdx.y * 64;
    int tid = threadIdx.x;
    int rr = tid >> 4, cc = (tid & 15) * 4;
#pragma unroll
    for (int i = 0; i < 4; ++i) {
        int r = i * 16 + rr;
        float4 v = *(const float4*)(ie + (size_t)(r0 + r) * C + c0 + cc);
        tile[cc + 0][r] = f2bf(v.x);
        tile[cc + 1][r] = f2bf(v.y);
        tile[cc + 2][r] = f2bf(v.z);
        tile[cc + 3][r] = f2bf(v.w);
    }
    __syncthreads();
    int oc = tid >> 3, orr = (tid & 7) * 8;
#pragma unroll
    for (int i = 0; i < 2; ++i) {
        int c = i * 32 + oc;
        uint4 v = *(const uint4*)&tile[c][orr];
        *(uint4*)(oe + (size_t)(c0 + c) * R + r0 + orr) = v;
    }
}

// ---------------- f32 -> bf16 convert (contiguous) ----------------
__global__ __launch_bounds__(256) void convert_kernel(
    const float* __restrict__ in, ushort* __restrict__ out)
{
    int i = (blockIdx.x * 256 + threadIdx.x) * 8;
    float4 a = *(const float4*)(in + i);
    float4 b = *(const float4*)(in + i + 4);
    ushort o[8];
    o[0] = f2bf(a.x); o[1] = f2bf(a.y); o[2] = f2bf(a.z); o[3] = f2bf(a.w);
    o[4] = f2bf(b.x); o[5] = f2bf(b.y); o[6] = f2bf(b.z); o[7] = f2bf(b.w);
    *(uint4*)(out + i) = *(uint4*)o;
}

// ---------------- gather tokens -> dense bf16 [E*CAPE][DIM], zero-fill ----------------
__global__ __launch_bounds__(256) void gather_kernel(
    const float* __restrict__ x, const int* __restrict__ assign_token,
    const int* __restrict__ nvalid, ushort* __restrict__ xg)
{
    int slot = blockIdx.x;
    int e = slot >> 9, c = slot & (CAPE - 1);
    int tid = threadIdx.x;
    ushort o[8];
    if (c < nvalid[e]) {
        int tok = assign_token[slot];
        const float* src = x + (size_t)tok * DIM + tid * 8;
        float4 a = *(const float4*)src;
        float4 b = *(const float4*)(src + 4);
        o[0] = f2bf(a.x); o[1] = f2bf(a.y); o[2] = f2bf(a.z); o[3] = f2bf(a.w);
        o[4] = f2bf(b.x); o[5] = f2bf(b.y); o[6] = f2bf(b.z); o[7] = f2bf(b.w);
    } else {
#pragma unroll
        for (int j = 0; j < 8; ++j) o[j] = 0;
    }
    *(uint4*)(xg + (size_t)slot * DIM + tid * 8) = *(uint4*)o;
}

// ---------------- bf16 MFMA GEMM, m97 structure: C = A @ B^T ----------------
// A: [M][K] bf16 (row stride K), B: [N][K] bf16 (row stride K)
// MODE 0: bf16 out; 1: bf16 out = silu(aux)*acc (in-place ok); 2: f32 out; 3: f32 out * rowscale[2*row]
template<int MODE>
__global__ __launch_bounds__(256) void gemm_bt(
    const ushort* __restrict__ A, const ushort* __restrict__ B,
    void* __restrict__ Out, const ushort* __restrict__ aux,
    const float* __restrict__ rowscale,
    int K, int outstride,
    size_t Aes, size_t Bes, size_t Oes, size_t Xes,
    const int* __restrict__ nvalid)
{
    int e = blockIdx.z;
    int bm = blockIdx.x * 128, bn = blockIdx.y * 128;
    if (nvalid && bm >= nvalid[e]) return;
    const ushort* Ae = A + (size_t)e * Aes;
    const ushort* Be = B + (size_t)e * Bes;

    __shared__ __align__(16) ushort As[128 * 64];
    __shared__ __align__(16) ushort Bs[128 * 64];

    int tid = threadIdx.x;
    int lane = tid & 63;
    int wr = (tid >> 7) & 1;
    int wc = (tid >> 6) & 1;

    f32x4 acc[4][4];
#pragma unroll
    for (int m = 0; m < 4; ++m)
#pragma unroll
        for (int n = 0; n < 4; ++n)
            acc[m][n] = (f32x4){0.f, 0.f, 0.f, 0.f};

    for (int k0 = 0; k0 < K; k0 += 64) {
#pragma unroll
        for (int j = 0; j < 4; ++j) {
            int c = j * 256 + tid;
            int r = c >> 3, ce = (c & 7) * 8;
            gload16(Ae + (size_t)(bm + r) * K + k0 + ce, &As[(c - lane) * 8]);
        }
#pragma unroll
        for (int j = 0; j < 4; ++j) {
            int c = j * 256 + tid;
            int r = c >> 3, ce = (c & 7) * 8;
            gload16(Be + (size_t)(bn + r) * K + k0 + ce, &Bs[(c - lane) * 8]);
        }
        __syncthreads();
#pragma unroll
        for (int ks = 0; ks < 2; ++ks) {
            int kb = ks * 32 + (lane >> 4) * 8;
            bf16x8 a[4], b[4];
#pragma unroll
            for (int m = 0; m < 4; ++m)
                a[m] = *(const bf16x8*)&As[(wr * 64 + m * 16 + (lane & 15)) * 64 + kb];
#pragma unroll
            for (int n = 0; n < 4; ++n)
                b[n] = *(const bf16x8*)&Bs[(wc * 64 + n * 16 + (lane & 15)) * 64 + kb];
#pragma unroll
            for (int m = 0; m < 4; ++m)
#pragma unroll
                for (int n = 0; n < 4; ++n)
                    acc[m][n] = __builtin_amdgcn_mfma_f32_16x16x32_bf16(a[m], b[n], acc[m][n], 0, 0, 0);
        }
        __syncthreads();
    }

    ushort* Ob = (ushort*)Out + (size_t)e * Oes;
    float*  Of = (float*)Out + (size_t)e * Oes;
    const ushort* Xe = aux + (size_t)e * Xes;
    int rbase = bm + wr * 64 + (lane >> 4) * 4;
    int cbase = bn + wc * 64 + (lane & 15);
#pragma unroll
    for (int m = 0; m < 4; ++m) {
#pragma unroll
        for (int n = 0; n < 4; ++n) {
            int col = cbase + n * 16;
#pragma unroll
            for (int r = 0; r < 4; ++r) {
                int row = rbase + m * 16 + r;
                float v = acc[m][n][r];
                if (MODE == 0) {
                    Ob[(size_t)row * outstride + col] = f2bf(v);
                } else if (MODE == 1) {
                    float g = bf2f(Xe[(size_t)row * outstride + col]);
                    float s = g / (1.f + __expf(-g));
                    Ob[(size_t)row * outstride + col] = f2bf(s * v);
                } else if (MODE == 2) {
                    Of[(size_t)row * outstride + col] = v;
                } else {
                    Of[(size_t)row * outstride + col] = v * rowscale[2 * row];
                }
            }
        }
    }
}

// ---------------- final combine: out += coef0*(w0*ye[s0] + w1*ye[s1]) ----------------
__global__ __launch_bounds__(256) void combine_kernel(
    const float* __restrict__ ye, const int* __restrict__ sidx,
    const float* __restrict__ swt, const float* __restrict__ coefo,
    float* __restrict__ out)
{
    int idx = blockIdx.x * 256 + threadIdx.x;
    int t = idx >> 9;
    int d = (idx & 511) << 2;
    int s0 = sidx[t * 2], s1 = sidx[t * 2 + 1];
    float c0 = coefo[t * 2];
    float w0 = swt[t * 2] * c0, w1 = swt[t * 2 + 1] * c0;
    float4 v = *(float4*)(out + (size_t)t * DIM + d);
    if (s0 >= 0) {
        float4 y = *(const float4*)(ye + (size_t)s0 * DIM + d);
        v.x += w0 * y.x; v.y += w0 * y.y; v.z += w0 * y.z; v.w += w0 * y.w;
    }
    if (s1 >= 0) {
        float4 y = *(const float4*)(ye + (size_t)s1 * DIM + d);
        v.x += w1 * y.x; v.y += w1 * y.y; v.z += w1 * y.z; v.w += w1 * y.w;
    }
    *(float4*)(out + (size_t)t * DIM + d) = v;
}

extern "C" void kernel_launch(void* const* d_in, const int* in_sizes, int n_in,
                              void* d_out, int out_size, void* d_ws, size_t ws_size,
                              hipStream_t stream)
{
    const float* x      = (const float*)d_in[0];
    const float* gate_w = (const float*)d_in[1];
    const float* w1     = (const float*)d_in[2];
    const float* w3     = (const float*)d_in[3];
    const float* w2     = (const float*)d_in[4];
    const float* sw1    = (const float*)d_in[5];
    const float* sw3    = (const float*)d_in[6];
    const float* sw2    = (const float*)d_in[7];
    const float* coef_w = (const float*)d_in[8];
    const float* coef_b = (const float*)d_in[9];
    float* out = (float*)d_out;

    char* ws = (char*)d_ws;
    size_t off = 0;
    auto alloc = [&](size_t bytes) -> void* {
        void* p = ws + off;
        off += (bytes + 255) & ~(size_t)255;
        return p;
    };
    float*  probs_sum    = (float*)alloc(NE * 4);
    int*    nvalid       = (int*)alloc(NE * 4);
    int*    topidx       = (int*)alloc((size_t)T_TOK * 2 * 4);
    float*  gatesw       = (float*)alloc((size_t)T_TOK * 2 * 4);
    float*  coefo        = (float*)alloc((size_t)T_TOK * 2 * 4);
    int*    sidx         = (int*)alloc((size_t)T_TOK * 2 * 4);
    float*  swt          = (float*)alloc((size_t)T_TOK * 2 * 4);
    int*    assign_token = (int*)alloc((size_t)NE * CAPE * 4);
    float*  logits       = (float*)alloc((size_t)T_TOK * 18 * 4);
    ushort* w1T  = (ushort*)alloc((size_t)NE * HID * DIM * 2);
    ushort* w3T  = (ushort*)alloc((size_t)NE * HID * DIM * 2);
    ushort* w2T  = (ushort*)alloc((size_t)NE * DIM * HID * 2);
    ushort* sw1T = (ushort*)alloc((size_t)HID * DIM * 2);
    ushort* sw3T = (ushort*)alloc((size_t)HID * DIM * 2);
    ushort* sw2T = (ushort*)alloc((size_t)DIM * HID * 2);
    ushort* xb   = (ushort*)alloc((size_t)T_TOK * DIM * 2);
    ushort* xg   = (ushort*)alloc((size_t)NE * CAPE * DIM * 2);
    ushort* h1   = (ushort*)alloc((size_t)T_TOK * HID * 2);
    ushort* he1  = (ushort*)alloc((size_t)NE * CAPE * HID * 2);
    float*  ye   = (float*)alloc((size_t)NE * CAPE * DIM * 4);

    hipMemsetAsync(probs_sum, 0, NE * 4, stream);
    logits_kernel<<<T_TOK / 4, 256, 0, stream>>>(x, gate_w, coef_w, logits);
    finish_kernel<<<T_TOK / 256, 256, 0, stream>>>(logits, coef_b,
                                                   topidx, gatesw, coefo, probs_sum);
    scan_kernel<<<1, 256, 0, stream>>>(topidx, gatesw, probs_sum,
                                       sidx, swt, assign_token, nvalid,
                                       out + (size_t)T_TOK * DIM);

    // weight transposes + x convert
    transpose_kernel<<<dim3(DIM/64, HID/64, NE), 256, 0, stream>>>(w1, w1T, DIM, HID, (size_t)DIM*HID, (size_t)HID*DIM);
    transpose_kernel<<<dim3(DIM/64, HID/64, NE), 256, 0, stream>>>(w3, w3T, DIM, HID, (size_t)DIM*HID, (size_t)HID*DIM);
    transpose_kernel<<<dim3(HID/64, DIM/64, NE), 256, 0, stream>>>(w2, w2T, HID, DIM, (size_t)HID*DIM, (size_t)DIM*HID);
    transpose_kernel<<<dim3(DIM/64, HID/64, 1), 256, 0, stream>>>(sw1, sw1T, DIM, HID, 0, 0);
    transpose_kernel<<<dim3(DIM/64, HID/64, 1), 256, 0, stream>>>(sw3, sw3T, DIM, HID, 0, 0);
    transpose_kernel<<<dim3(HID/64, DIM/64, 1), 256, 0, stream>>>(sw2, sw2T, HID, DIM, 0, 0);
    convert_kernel<<<(T_TOK * DIM) / (256 * 8), 256, 0, stream>>>(x, xb);
    gather_kernel<<<NE * CAPE, 256, 0, stream>>>(x, assign_token, nvalid, xg);

    // shared MLP: h1 = xb@sw1T; h1 = silu(h1)*(xb@sw3T); out = (h1@sw2T)*c1
    gemm_bt<0><<<dim3(T_TOK/128, HID/128, 1), 256, 0, stream>>>(
        xb, sw1T, h1, h1, nullptr, DIM, HID, 0, 0, 0, 0, nullptr);
    gemm_bt<1><<<dim3(T_TOK/128, HID/128, 1), 256, 0, stream>>>(
        xb, sw3T, h1, h1, nullptr, DIM, HID, 0, 0, 0, 0, nullptr);

    // experts: he1 = xg@w1T; he1 = silu(he1)*(xg@w3T); ye = he1@w2T
    gemm_bt<0><<<dim3(CAPE/128, HID/128, NE), 256, 0, stream>>>(
        xg, w1T, he1, he1, nullptr, DIM, HID,
        (size_t)CAPE*DIM, (size_t)HID*DIM, (size_t)CAPE*HID, (size_t)CAPE*HID, nvalid);
    gemm_bt<1><<<dim3(CAPE/128, HID/128, NE), 256, 0, stream>>>(
        xg, w3T, he1, he1, nullptr, DIM, HID,
        (size_t)CAPE*DIM, (size_t)HID*DIM, (size_t)CAPE*HID, (size_t)CAPE*HID, nvalid);
    gemm_bt<2><<<dim3(CAPE/128, DIM/128, NE), 256, 0, stream>>>(
        he1, w2T, ye, he1, nullptr, HID, DIM,
        (size_t)CAPE*HID, (size_t)DIM*HID, (size_t)CAPE*DIM, 0, nvalid);

    gemm_bt<3><<<dim3(T_TOK/128, DIM/128, 1), 256, 0, stream>>>(
        h1, sw2T, out, h1, coefo + 1, HID, DIM, 0, 0, 0, 0, nullptr);

    combine_kernel<<<(T_TOK * (DIM / 4)) / 256, 256, 0, stream>>>(ye, sidx, swt, coefo, out);
}